// Round 1
// baseline (250.850 us; speedup 1.0000x reference)
//
#include <hip/hip_runtime.h>
#include <math.h>

// NeuralSurfaceReconstructor: one wave (64 lanes) per ray.
// Lane i (< 51) computes sigmoid(SDF) at sample i; lanes < 50 also compute
// the MLP RGB at the segment start. Alpha-compositing cumprod is a wave
// shfl_up scan; final color is a wave reduce.

#define NP1 51
#define NSTEP 50
#define FGS 192
#define BGS 128
#define HID 64
#define WAVES_PER_BLOCK 4

__device__ __forceinline__ float tri1(const float* __restrict__ g, int S,
                                      float px, float py, float pz) {
    const float sf = (float)(S - 1);
    float cx = fminf(fmaxf((px + 1.f) * 0.5f * sf, 0.f), sf);
    float cy = fminf(fmaxf((py + 1.f) * 0.5f * sf, 0.f), sf);
    float cz = fminf(fmaxf((pz + 1.f) * 0.5f * sf, 0.f), sf);
    float fx0 = floorf(cx), fy0 = floorf(cy), fz0 = floorf(cz);
    int ix0 = (int)fx0, iy0 = (int)fy0, iz0 = (int)fz0;
    int ix1 = min(ix0 + 1, S - 1), iy1 = min(iy0 + 1, S - 1), iz1 = min(iz0 + 1, S - 1);
    float wx = cx - fx0, wy = cy - fy0, wz = cz - fz0;
    float ux = 1.f - wx, uy = 1.f - wy, uz = 1.f - wz;
    long b00 = ((long)ix0 * S + iy0) * S;
    long b01 = ((long)ix0 * S + iy1) * S;
    long b10 = ((long)ix1 * S + iy0) * S;
    long b11 = ((long)ix1 * S + iy1) * S;
    float v = 0.f;
    v += g[b00 + iz0] * (ux * uy * uz);
    v += g[b00 + iz1] * (ux * uy * wz);
    v += g[b01 + iz0] * (ux * wy * uz);
    v += g[b01 + iz1] * (ux * wy * wz);
    v += g[b10 + iz0] * (wx * uy * uz);
    v += g[b10 + iz1] * (wx * uy * wz);
    v += g[b11 + iz0] * (wx * wy * uz);
    v += g[b11 + iz1] * (wx * wy * wz);
    return v;
}

__device__ __forceinline__ void tri3(const float* __restrict__ g, int S,
                                     float px, float py, float pz,
                                     float& o0, float& o1, float& o2) {
    const float sf = (float)(S - 1);
    float cx = fminf(fmaxf((px + 1.f) * 0.5f * sf, 0.f), sf);
    float cy = fminf(fmaxf((py + 1.f) * 0.5f * sf, 0.f), sf);
    float cz = fminf(fmaxf((pz + 1.f) * 0.5f * sf, 0.f), sf);
    float fx0 = floorf(cx), fy0 = floorf(cy), fz0 = floorf(cz);
    int ix0 = (int)fx0, iy0 = (int)fy0, iz0 = (int)fz0;
    int ix1 = min(ix0 + 1, S - 1), iy1 = min(iy0 + 1, S - 1), iz1 = min(iz0 + 1, S - 1);
    float wx = cx - fx0, wy = cy - fy0, wz = cz - fz0;
    float ux = 1.f - wx, uy = 1.f - wy, uz = 1.f - wz;
    long b00 = ((long)ix0 * S + iy0) * S;
    long b01 = ((long)ix0 * S + iy1) * S;
    long b10 = ((long)ix1 * S + iy0) * S;
    long b11 = ((long)ix1 * S + iy1) * S;
    float w000 = ux * uy * uz, w001 = ux * uy * wz;
    float w010 = ux * wy * uz, w011 = ux * wy * wz;
    float w100 = wx * uy * uz, w101 = wx * uy * wz;
    float w110 = wx * wy * uz, w111 = wx * wy * wz;
    long vox = (long)S * S * S;
    o0 = 0.f; o1 = 0.f; o2 = 0.f;
#pragma unroll
    for (int c = 0; c < 3; ++c) {
        const float* gc = g + (long)c * vox;
        float v = 0.f;
        v += gc[b00 + iz0] * w000;
        v += gc[b00 + iz1] * w001;
        v += gc[b01 + iz0] * w010;
        v += gc[b01 + iz1] * w011;
        v += gc[b10 + iz0] * w100;
        v += gc[b10 + iz1] * w101;
        v += gc[b11 + iz0] * w110;
        v += gc[b11 + iz1] * w111;
        if (c == 0) o0 = v; else if (c == 1) o1 = v; else o2 = v;
    }
}

__global__ __launch_bounds__(WAVES_PER_BLOCK * 64) void nsr_kernel(
    const float* __restrict__ x,
    const float* __restrict__ fg_sdf, const float* __restrict__ fg_feat,
    const float* __restrict__ bg_sdf, const float* __restrict__ bg_feat,
    const float* __restrict__ w1, const float* __restrict__ b1,
    const float* __restrict__ w2, const float* __restrict__ b2,
    float* __restrict__ out, int R) {
    __shared__ float sw1[3 * HID];
    __shared__ float sb1[HID];
    __shared__ float sw2[HID * 3];
    __shared__ float sb2[3];
    for (int i = threadIdx.x; i < 3 * HID; i += blockDim.x) sw1[i] = w1[i];
    for (int i = threadIdx.x; i < HID; i += blockDim.x) sb1[i] = b1[i];
    for (int i = threadIdx.x; i < HID * 3; i += blockDim.x) sw2[i] = w2[i];
    if (threadIdx.x < 3) sb2[threadIdx.x] = b2[threadIdx.x];
    __syncthreads();

    const int lane = threadIdx.x & 63;
    const int wave = threadIdx.x >> 6;
    const int ray = blockIdx.x * WAVES_PER_BLOCK + wave;
    if (ray >= R) return;

    float sig = 1.f;
    float r0 = 0.f, r1 = 0.f, r2 = 0.f;

    if (lane < NP1) {
        const float* xp = x + ((long)ray * NP1 + lane) * 3;
        float px = xp[0], py = xp[1], pz = xp[2];
        float ax = fabsf(px), ay = fabsf(py), az = fabsf(pz);
        bool is_f = (ax < 1.f) & (ay < 1.f) & (az < 1.f);
        bool is_b = (!is_f) & (ax < 4.f) & (ay < 4.f) & (az < 4.f);

        float s;
        if (is_f)      s = tri1(fg_sdf, FGS, px, py, pz);
        else if (is_b) s = tri1(bg_sdf, BGS, px * 0.25f, py * 0.25f, pz * 0.25f);
        else           s = 1.f;
        sig = 1.f / (1.f + expf(-s));

        if (lane < NSTEP) {
            float f0 = 0.5f, f1 = 0.5f, f2 = 0.5f;
            if (is_f)      tri3(fg_feat, FGS, px, py, pz, f0, f1, f2);
            else if (is_b) tri3(bg_feat, BGS, px * 0.25f, py * 0.25f, pz * 0.25f, f0, f1, f2);
            // MLP: relu(f @ w1 + b1) @ w2 + b2
            float a0 = sb2[0], a1 = sb2[1], a2 = sb2[2];
#pragma unroll 8
            for (int j = 0; j < HID; ++j) {
                float h = fmaf(sw1[j], f0,
                          fmaf(sw1[HID + j], f1,
                          fmaf(sw1[2 * HID + j], f2, sb1[j])));
                h = fmaxf(h, 0.f);
                a0 = fmaf(h, sw2[j * 3 + 0], a0);
                a1 = fmaf(h, sw2[j * 3 + 1], a1);
                a2 = fmaf(h, sw2[j * 3 + 2], a2);
            }
            r0 = a0; r1 = a1; r2 = a2;
        }
    }

    // alpha_i = relu((sig_i - sig_{i+1}) / sig_i), i < 50
    float sig_next = __shfl_down(sig, 1, 64);
    float alpha = 0.f;
    if (lane < NSTEP) alpha = fmaxf(0.f, (sig - sig_next) / sig);
    float t = 1.f - alpha;  // lanes >= NSTEP: t = 1 (neutral for scan)

    // inclusive scan product over lanes
    float p = t;
#pragma unroll
    for (int d = 1; d < 64; d <<= 1) {
        float v = __shfl_up(p, d, 64);
        if (lane >= d) p *= v;
    }
    // exclusive: T_0 = 1, T_i = P_{i-1}
    float T = __shfl_up(p, 1, 64);
    if (lane == 0) T = 1.f;

    float w = (lane < NSTEP) ? T * alpha : 0.f;
    float c0 = w * r0, c1 = w * r1, c2 = w * r2;
#pragma unroll
    for (int d = 32; d >= 1; d >>= 1) {
        c0 += __shfl_down(c0, d, 64);
        c1 += __shfl_down(c1, d, 64);
        c2 += __shfl_down(c2, d, 64);
    }
    if (lane == 0) {
        out[(long)ray * 3 + 0] = c0;
        out[(long)ray * 3 + 1] = c1;
        out[(long)ray * 3 + 2] = c2;
    }
}

extern "C" void kernel_launch(void* const* d_in, const int* in_sizes, int n_in,
                              void* d_out, int out_size, void* d_ws, size_t ws_size,
                              hipStream_t stream) {
    const float* x       = (const float*)d_in[0];
    // d_in[1] = v (unused by the reference MLP)
    const float* fg_sdf  = (const float*)d_in[2];
    const float* fg_feat = (const float*)d_in[3];
    const float* bg_sdf  = (const float*)d_in[4];
    const float* bg_feat = (const float*)d_in[5];
    const float* w1      = (const float*)d_in[6];
    const float* b1      = (const float*)d_in[7];
    const float* w2      = (const float*)d_in[8];
    const float* b2      = (const float*)d_in[9];
    float* out = (float*)d_out;

    int R = in_sizes[0] / (NP1 * 3);  // 8192
    int grid = (R + WAVES_PER_BLOCK - 1) / WAVES_PER_BLOCK;
    nsr_kernel<<<grid, WAVES_PER_BLOCK * 64, 0, stream>>>(
        x, fg_sdf, fg_feat, bg_sdf, bg_feat, w1, b1, w2, b2, out, R);
}